// Round 1
// baseline (3099.025 us; speedup 1.0000x reference)
//
#include <hip/hip_runtime.h>

#define NA   16384
#define NE   524288
#define NM   256
#define FF   4800
#define HH   512
#define NMX  10
#define NSPH 9

typedef __bf16 bf16x8 __attribute__((ext_vector_type(8)));
typedef float  f32x4  __attribute__((ext_vector_type(4)));

__device__ inline unsigned short f2bf(float x){
  unsigned int u = __builtin_bit_cast(unsigned int, x);
  u += 0x7fffu + ((u >> 16) & 1u);
  return (unsigned short)(u >> 16);
}
__device__ inline float bf2f(unsigned short h){
  unsigned int u = ((unsigned int)h) << 16;
  return __builtin_bit_cast(float, u);
}
__device__ inline void atomic_add_f(float* p, float v){
  __hip_atomic_fetch_add(p, v, __ATOMIC_RELAXED, __HIP_MEMORY_SCOPE_AGENT);
}
__device__ inline void gload16(const void* g, void* l){
  __builtin_amdgcn_global_load_lds(
      (const __attribute__((address_space(1))) unsigned int*)g,
      (__attribute__((address_space(3))) unsigned int*)l, 16, 0, 0);
}
__device__ inline float silu(float x){ return x / (1.f + __expf(-x)); }

// ---------------- edge scatter: cs[atom][species][10*9] ----------------
__global__ __launch_bounds__(256) void k_edges(
    const float* __restrict__ pos, const float* __restrict__ cells,
    const int* __restrict__ numbers, const int* __restrict__ ei,
    const float* __restrict__ eoff, const int* __restrict__ batch,
    float* __restrict__ cs)
{
  int e = blockIdx.x * 256 + threadIdx.x;
  if (e >= NE) return;
  int snd = ei[e], rcv = ei[NE + e];
  const float* C = cells + (size_t)batch[snd] * 9;
  float o0 = eoff[e*3+0], o1 = eoff[e*3+1], o2 = eoff[e*3+2];
  float rx = pos[rcv*3+0] - pos[snd*3+0] + o0*C[0] + o1*C[3] + o2*C[6];
  float ry = pos[rcv*3+1] - pos[snd*3+1] + o0*C[1] + o1*C[4] + o2*C[7];
  float rz = pos[rcv*3+2] - pos[snd*3+2] + o0*C[2] + o1*C[5] + o2*C[8];
  float r = sqrtf(rx*rx + ry*ry + rz*rz + 1e-12f);
  float inv = 1.f / r;
  float hx = rx*inv, hy = ry*inv, hz = rz*inv;
  float fc = (r < 5.f) ? (0.5f * (__cosf(r * 0.6283185307179586f) + 1.f)) : 0.f;
  float R[NMX];
  #pragma unroll
  for (int n = 0; n < NMX; n++){
    float d = r - (5.f/9.f) * (float)n;
    R[n] = __expf(-2.f * d * d) * fc;
  }
  float Y[NSPH];
  Y[0] = 0.28209479177387814f;
  Y[1] = 0.4886025119029199f * hy;
  Y[2] = 0.4886025119029199f * hz;
  Y[3] = 0.4886025119029199f * hx;
  Y[4] = 1.0925484305920792f * hx * hy;
  Y[5] = 1.0925484305920792f * hy * hz;
  Y[6] = 0.31539156525252005f * (3.f * hz * hz - 1.f);
  Y[7] = 1.0925484305920792f * hx * hz;
  Y[8] = 0.5462742152960396f * (hx * hx - hy * hy);
  int sp = numbers[snd];
  float* base = cs + (size_t)rcv * 360 + sp * 90;
  #pragma unroll
  for (int n = 0; n < NMX; n++){
    #pragma unroll
    for (int k = 0; k < NSPH; k++)
      atomic_add_f(base + n*9 + k, R[n] * Y[k]);
  }
}

// ---------------- species grouping ----------------
__global__ void k_count(const int* __restrict__ numbers, int* __restrict__ cnt){
  int i = blockIdx.x * 256 + threadIdx.x;
  if (i < NA) atomicAdd(&cnt[numbers[i]], 1);
}
__global__ void k_offs(const int* __restrict__ cnt, int* __restrict__ offs){
  if (threadIdx.x == 0){
    int o = 0;
    for (int s = 0; s < 4; s++){ offs[s] = o; o += cnt[s]; }
    offs[4] = o;
  }
}
__global__ void k_scatter(const int* __restrict__ numbers, const int* __restrict__ offs,
                          int* __restrict__ cursor, int* __restrict__ list){
  int i = blockIdx.x * 256 + threadIdx.x;
  if (i < NA){
    int s = numbers[i];
    int p = atomicAdd(&cursor[s], 1);
    list[offs[s] + p] = i;
  }
}

// ---------------- per-atom: mix cs->c, compute ps (bf16) + LN stats ----------------
__global__ __launch_bounds__(256) void k_ps(
    const float* __restrict__ cs, const float* __restrict__ U,
    unsigned short* __restrict__ ps, float* __restrict__ stats)
{
  __shared__ float csr[360];
  __shared__ float cl[360];
  __shared__ float red[16];
  __shared__ float ul[16];
  int i = blockIdx.x, tid = threadIdx.x;
  if (tid < 16) ul[tid] = U[tid];
  for (int j = tid; j < 360; j += 256) csr[j] = cs[(size_t)i * 360 + j];
  __syncthreads();
  for (int j = tid; j < 360; j += 256){
    int a = j / 90, nk = j % 90;
    cl[j] = ul[a*4+0]*csr[nk] + ul[a*4+1]*csr[90+nk]
          + ul[a*4+2]*csr[180+nk] + ul[a*4+3]*csr[270+nk];
  }
  __syncthreads();
  float s1 = 0.f, s2 = 0.f;
  const float rs3 = 0.5773502691896258f, rs5 = 0.4472135954999579f;
  for (int f = tid; f < FF; f += 256){
    int l = f % 3, qp = f / 3;
    int q = qp / 40, p = qp - q * 40;
    const float* cq = &cl[q * 9];
    const float* cp = &cl[p * 9];
    float v;
    if (l == 0)      v = cq[0]*cp[0];
    else if (l == 1) v = (cq[1]*cp[1] + cq[2]*cp[2] + cq[3]*cp[3]) * rs3;
    else             v = (cq[4]*cp[4] + cq[5]*cp[5] + cq[6]*cp[6] + cq[7]*cp[7] + cq[8]*cp[8]) * rs5;
    ps[(size_t)i * FF + f] = f2bf(v);
    s1 += v; s2 += v * v;
  }
  #pragma unroll
  for (int m = 32; m; m >>= 1){ s1 += __shfl_xor(s1, m, 64); s2 += __shfl_xor(s2, m, 64); }
  int w = tid >> 6, lane = tid & 63;
  if (lane == 0){ red[w] = s1; red[8 + w] = s2; }
  __syncthreads();
  if (tid == 0){
    float t1 = red[0] + red[1] + red[2] + red[3];
    float t2 = red[8] + red[9] + red[10] + red[11];
    float mean = t1 * (1.f / FF);
    float var = t2 * (1.f / FF) - mean * mean;
    var = fmaxf(var, 0.f);
    stats[2*i]   = mean;
    stats[2*i+1] = rsqrtf(var + 1e-5f);
  }
}

// ---------------- weight prep: Wg1[s][n][f] = gamma[f]*sum_a U[a,s]W1[a][f][n] (bf16),
//                  plus column sums gW (gamma-weighted) and bW (beta-weighted) ----------
__global__ __launch_bounds__(256) void k_wg1(
    const float* __restrict__ W1, const float* __restrict__ U,
    const float* __restrict__ gamma, const float* __restrict__ beta,
    unsigned short* __restrict__ Wg, float* __restrict__ gW, float* __restrict__ bW)
{
  __shared__ float tg[64][65];
  __shared__ float tb[64][65];
  int n0 = blockIdx.x * 64, f0 = blockIdx.y * 64, s = blockIdx.z;
  float u0 = U[s], u1 = U[4+s], u2 = U[8+s], u3 = U[12+s];
  int tid = threadIdx.x;
  #pragma unroll 4
  for (int rep = 0; rep < 16; rep++){
    int idx = rep * 256 + tid;
    int fi = idx >> 6, ni = idx & 63;
    size_t base = (size_t)(f0 + fi) * 512 + (n0 + ni);
    float w = u0*W1[base] + u1*W1[base + (size_t)FF*512]
            + u2*W1[base + (size_t)2*FF*512] + u3*W1[base + (size_t)3*FF*512];
    tg[fi][ni] = gamma[f0 + fi] * w;
    tb[fi][ni] = beta[f0 + fi] * w;
  }
  __syncthreads();
  #pragma unroll 4
  for (int rep = 0; rep < 16; rep++){
    int idx = rep * 256 + tid;
    int ni = idx >> 6, fi = idx & 63;
    Wg[((size_t)s * 512 + n0 + ni) * FF + f0 + fi] = f2bf(tg[fi][ni]);
  }
  if (tid < 64){
    float sg = 0.f, sb = 0.f;
    for (int fi = 0; fi < 64; fi++){ sg += tg[fi][tid]; sb += tb[fi][tid]; }
    atomic_add_f(&gW[s * 512 + n0 + tid], sg);
    atomic_add_f(&bW[s * 512 + n0 + tid], sb);
  }
}

// ---------------- W2t[s][n][k] = sum_a U[a,s] W2[a][k][n] (bf16) ----------------
__global__ __launch_bounds__(256) void k_w2t(
    const float* __restrict__ W2, const float* __restrict__ U,
    unsigned short* __restrict__ W2t)
{
  __shared__ float t[64][65];
  int n0 = blockIdx.x * 64, k0 = blockIdx.y * 64, s = blockIdx.z;
  float u0 = U[s], u1 = U[4+s], u2 = U[8+s], u3 = U[12+s];
  int tid = threadIdx.x;
  #pragma unroll 4
  for (int rep = 0; rep < 16; rep++){
    int idx = rep * 256 + tid;
    int ki = idx >> 6, ni = idx & 63;
    size_t base = (size_t)(k0 + ki) * 512 + (n0 + ni);
    t[ki][ni] = u0*W2[base] + u1*W2[base + 512*512]
              + u2*W2[base + 2*512*512] + u3*W2[base + 3*512*512];
  }
  __syncthreads();
  #pragma unroll 4
  for (int rep = 0; rep < 16; rep++){
    int idx = rep * 256 + tid;
    int ni = idx >> 6, ki = idx & 63;
    W2t[((size_t)s * 512 + n0 + ni) * 512 + k0 + ki] = f2bf(t[ki][ni]);
  }
}

__global__ void k_w3(const float* __restrict__ W3, const float* __restrict__ U,
                     float* __restrict__ W3s)
{
  int idx = blockIdx.x * 256 + threadIdx.x;
  if (idx < 4 * 512){
    int s = idx >> 9, k = idx & 511;
    W3s[idx] = U[s]*W3[k] + U[4+s]*W3[512+k] + U[8+s]*W3[2*512+k] + U[12+s]*W3[3*512+k];
  }
}

// ---------------- GEMM: gathered rows (species-grouped) x Bt[s][N][K], bf16 MFMA ------
// EPI==1: LN-affine epilogue + silu -> h1.  EPI==2: silu -> h2.
template<int EPI>
__global__ __launch_bounds__(256) void k_gemm(
    const unsigned short* __restrict__ Ag, int lda, int K,
    const unsigned short* __restrict__ Btg,
    const int* __restrict__ list, const int* __restrict__ offs, const int* __restrict__ cnt,
    const float* __restrict__ stats, const float* __restrict__ gW, const float* __restrict__ bW,
    unsigned short* __restrict__ out)
{
  __shared__ alignas(16) char smem[32768]; // A: [128][64]bf16 (16KB) + B: [128][64]bf16
  int t = blockIdx.x, s = 0;
  for (; s < 4; s++){
    int nts = (cnt[s] + 127) >> 7;
    if (t < nts) break;
    t -= nts;
  }
  if (s >= 4) return;
  int cntS = cnt[s], offS = offs[s];
  int rt = t, n0 = blockIdx.y * 128;
  int tid = threadIdx.x, w = tid >> 6, lane = tid & 63;
  int wr = w >> 1, wc = w & 1;

  const unsigned short* Bts = Btg + (size_t)s * 512 * K;
  const unsigned short* gA[4];
  const unsigned short* gB[4];
  char* lA[4];
  char* lB[4];
  #pragma unroll
  for (int it = 0; it < 4; it++){
    int g = it * 4 + w;
    int idx = g * 64 + lane;
    int row = idx >> 3, ch = idx & 7;
    int cg = ch ^ (row & 7);
    int gr = rt * 128 + row; gr = gr < cntS ? gr : cntS - 1;
    int atom = list[offS + gr];
    gA[it] = Ag + (size_t)atom * lda + cg * 8;
    lA[it] = smem + g * 1024;
    gB[it] = Bts + (size_t)(n0 + row) * K + cg * 8;
    lB[it] = smem + 16384 + g * 1024;
  }

  int hi = lane >> 4, lo = lane & 15;
  f32x4 acc[4][4];
  #pragma unroll
  for (int mi = 0; mi < 4; mi++)
    #pragma unroll
    for (int ni = 0; ni < 4; ni++)
      #pragma unroll
      for (int r = 0; r < 4; r++) acc[mi][ni][r] = 0.f;

  int abase[4], a7[4], bbase[4], b7[4];
  #pragma unroll
  for (int mi = 0; mi < 4; mi++){ int row = wr*64 + mi*16 + lo; abase[mi] = row*128; a7[mi] = row & 7; }
  #pragma unroll
  for (int ni = 0; ni < 4; ni++){ int row = wc*64 + ni*16 + lo; bbase[ni] = 16384 + row*128; b7[ni] = row & 7; }

  for (int kt = 0; kt < K; kt += 64){
    #pragma unroll
    for (int it = 0; it < 4; it++) gload16(gA[it] + kt, lA[it]);
    #pragma unroll
    for (int it = 0; it < 4; it++) gload16(gB[it] + kt, lB[it]);
    __syncthreads();
    #pragma unroll
    for (int kk = 0; kk < 2; kk++){
      bf16x8 af[4], bfr[4];
      #pragma unroll
      for (int mi = 0; mi < 4; mi++)
        af[mi] = *(const bf16x8*)(smem + abase[mi] + (((kk*4 + hi) ^ a7[mi]) << 4));
      #pragma unroll
      for (int ni = 0; ni < 4; ni++)
        bfr[ni] = *(const bf16x8*)(smem + bbase[ni] + (((kk*4 + hi) ^ b7[ni]) << 4));
      #pragma unroll
      for (int mi = 0; mi < 4; mi++)
        #pragma unroll
        for (int ni = 0; ni < 4; ni++)
          acc[mi][ni] = __builtin_amdgcn_mfma_f32_16x16x32_bf16(af[mi], bfr[ni], acc[mi][ni], 0, 0, 0);
    }
    __syncthreads();
  }

  int gn[4]; float gwv[4], bwv[4];
  #pragma unroll
  for (int ni = 0; ni < 4; ni++){
    gn[ni] = n0 + wc*64 + ni*16 + lo;
    if (EPI == 1){ gwv[ni] = gW[s*512 + gn[ni]]; bwv[ni] = bW[s*512 + gn[ni]]; }
    else { gwv[ni] = 0.f; bwv[ni] = 0.f; }
  }
  #pragma unroll
  for (int mi = 0; mi < 4; mi++){
    #pragma unroll
    for (int j = 0; j < 4; j++){
      int gr = rt*128 + wr*64 + mi*16 + hi*4 + j;
      if (gr < cntS){
        int atom = list[offS + gr];
        float mean = 0.f, rstd = 0.f;
        if (EPI == 1){ mean = stats[2*atom]; rstd = stats[2*atom+1]; }
        #pragma unroll
        for (int ni = 0; ni < 4; ni++){
          float v = acc[mi][ni][j];
          if (EPI == 1) v = rstd * v + bwv[ni] - mean * rstd * gwv[ni];
          v = silu(v);
          out[(size_t)atom * 512 + gn[ni]] = f2bf(v);
        }
      }
    }
  }
}

// ---------------- final: per-atom dot(h2, W3s[s]) -> molecule segment sum -------------
__global__ __launch_bounds__(256) void k_final(
    const unsigned short* __restrict__ h2, const float* __restrict__ W3s,
    const int* __restrict__ numbers, const int* __restrict__ batch,
    const float* __restrict__ Wc, float* __restrict__ out)
{
  int wid = threadIdx.x >> 6, lane = threadIdx.x & 63;
  int atom = blockIdx.x * 4 + wid;
  if (atom >= NA) return;
  int sp = numbers[atom];
  const unsigned short* hp = h2 + (size_t)atom * 512 + lane * 8;
  const float* wp = W3s + sp * 512 + lane * 8;
  float acc = 0.f;
  #pragma unroll
  for (int j = 0; j < 8; j++) acc += bf2f(hp[j]) * wp[j];
  #pragma unroll
  for (int m = 32; m; m >>= 1) acc += __shfl_xor(acc, m, 64);
  if (lane == 0){
    float val = acc * (1.f / 128.f) + Wc[sp]; // /sqrt(A)/AVG_ATOMS + comp@Wc.T
    atomic_add_f(&out[batch[atom]], val);
  }
}

extern "C" void kernel_launch(void* const* d_in, const int* in_sizes, int n_in,
                              void* d_out, int out_size, void* d_ws, size_t ws_size,
                              hipStream_t stream)
{
  const float* pos     = (const float*)d_in[0];
  const float* cells   = (const float*)d_in[1];
  const int*   numbers = (const int*)d_in[2];
  const int*   ei      = (const int*)d_in[3];
  const float* eoff    = (const float*)d_in[4];
  const int*   batch   = (const int*)d_in[5];
  const float* U       = (const float*)d_in[6];
  const float* gamma   = (const float*)d_in[7];
  const float* beta    = (const float*)d_in[8];
  const float* W1      = (const float*)d_in[9];
  const float* W2      = (const float*)d_in[10];
  const float* W3      = (const float*)d_in[11];
  const float* Wc      = (const float*)d_in[12];
  float* out = (float*)d_out;

  char* ws = (char*)d_ws;
  size_t off = 0;
  auto alloc = [&](size_t bytes) -> void* {
    void* p = ws + off;
    off += (bytes + 255) & ~(size_t)255;
    return p;
  };
  unsigned short* ps  = (unsigned short*)alloc((size_t)NA * FF * 2);   // 157 MB
  float* cs           = (float*)alloc((size_t)NA * 360 * 4);           // 23.6 MB
  float* stats        = (float*)alloc((size_t)NA * 2 * 4);
  unsigned short* Wg1 = (unsigned short*)alloc((size_t)4 * 512 * FF * 2); // 19.7 MB
  float* gW           = (float*)alloc(4 * 512 * 4);
  float* bW           = (float*)alloc(4 * 512 * 4);
  unsigned short* W2t = (unsigned short*)alloc((size_t)4 * 512 * 512 * 2);
  float* W3s          = (float*)alloc(4 * 512 * 4);
  unsigned short* h1  = (unsigned short*)alloc((size_t)NA * 512 * 2);
  unsigned short* h2  = (unsigned short*)alloc((size_t)NA * 512 * 2);
  int* list           = (int*)alloc(NA * 4);
  int* ints           = (int*)alloc(64);
  int* cnt = ints; int* cursor = ints + 4; int* offs = ints + 8;

  hipMemsetAsync(cs, 0, (size_t)NA * 360 * 4, stream);
  hipMemsetAsync(ints, 0, 64, stream);
  hipMemsetAsync(gW, 0, 4 * 512 * 4, stream);
  hipMemsetAsync(bW, 0, 4 * 512 * 4, stream);
  hipMemsetAsync(out, 0, (size_t)out_size * 4, stream);

  k_edges<<<NE / 256, 256, 0, stream>>>(pos, cells, numbers, ei, eoff, batch, cs);
  k_count<<<NA / 256, 256, 0, stream>>>(numbers, cnt);
  k_offs<<<1, 64, 0, stream>>>(cnt, offs);
  k_scatter<<<NA / 256, 256, 0, stream>>>(numbers, offs, cursor, list);
  k_ps<<<NA, 256, 0, stream>>>(cs, U, ps, stats);
  k_wg1<<<dim3(8, 75, 4), 256, 0, stream>>>(W1, U, gamma, beta, Wg1, gW, bW);
  k_w2t<<<dim3(8, 8, 4), 256, 0, stream>>>(W2, U, W2t);
  k_w3<<<8, 256, 0, stream>>>(W3, U, W3s);
  k_gemm<1><<<dim3(132, 4), 256, 0, stream>>>(ps, FF, FF, Wg1, list, offs, cnt, stats, gW, bW, h1);
  k_gemm<2><<<dim3(132, 4), 256, 0, stream>>>(h1, 512, 512, W2t, list, offs, cnt, stats, gW, bW, h2);
  k_final<<<NA / 4, 256, 0, stream>>>(h2, W3s, numbers, batch, Wc, out);
}

// Round 2
// 745.398 us; speedup vs baseline: 4.1575x; 4.1575x over previous
//
#include <hip/hip_runtime.h>

#define NA   16384
#define NE   524288
#define NM   256
#define FF   4800
#define HH   512
#define NMX  10
#define NSPH 9

typedef __bf16 bf16x8 __attribute__((ext_vector_type(8)));
typedef float  f32x4  __attribute__((ext_vector_type(4)));

__device__ inline unsigned short f2bf(float x){
  unsigned int u = __builtin_bit_cast(unsigned int, x);
  u += 0x7fffu + ((u >> 16) & 1u);
  return (unsigned short)(u >> 16);
}
__device__ inline float bf2f(unsigned short h){
  unsigned int u = ((unsigned int)h) << 16;
  return __builtin_bit_cast(float, u);
}
__device__ inline void atomic_add_f(float* p, float v){
  __hip_atomic_fetch_add(p, v, __ATOMIC_RELAXED, __HIP_MEMORY_SCOPE_AGENT);
}
__device__ inline void gload16(const void* g, void* l){
  __builtin_amdgcn_global_load_lds(
      (const __attribute__((address_space(1))) unsigned int*)g,
      (__attribute__((address_space(3))) unsigned int*)l, 16, 0, 0);
}
__device__ inline float silu(float x){ return x / (1.f + __expf(-x)); }

// ---------------- edge counting sort by recv ----------------
__global__ __launch_bounds__(256) void k_hist(const int* __restrict__ ei, int* __restrict__ cnt16k){
  int e = blockIdx.x * 256 + threadIdx.x;
  if (e < NE) atomicAdd(&cnt16k[ei[NE + e]], 1);
}

__global__ __launch_bounds__(256) void k_scan(const int* __restrict__ cnt16k,
                                              int* __restrict__ starts, int* __restrict__ cursor){
  __shared__ int part[256];
  int tid = threadIdx.x;
  int base = tid * 64;
  int s = 0;
  for (int j = 0; j < 64; j++) s += cnt16k[base + j];
  part[tid] = s;
  __syncthreads();
  if (tid == 0){
    int acc = 0;
    for (int i = 0; i < 256; i++){ int t = part[i]; part[i] = acc; acc += t; }
  }
  __syncthreads();
  int acc = part[tid];
  for (int j = 0; j < 64; j++){
    starts[base + j] = acc;
    cursor[base + j] = acc;
    acc += cnt16k[base + j];
  }
  if (tid == 255) starts[16384] = NE;
}

__global__ __launch_bounds__(256) void k_sortperm(const int* __restrict__ ei,
                                                  int* __restrict__ cursor, int* __restrict__ perm){
  int e = blockIdx.x * 256 + threadIdx.x;
  if (e < NE){
    int rcv = ei[NE + e];
    int p = atomicAdd(&cursor[rcv], 1);
    perm[p] = e;
  }
}

// ---------------- per-atom edge accumulation (no atomics) ----------------
// block = 384 threads; thread t<360 owns output slot (sp=t/90, n=(t%90)/9, k=t%9)
__global__ __launch_bounds__(384) void k_edges2(
    const float* __restrict__ pos, const float* __restrict__ cells,
    const int* __restrict__ numbers, const int* __restrict__ ei,
    const float* __restrict__ eoff, const int* __restrict__ batch,
    const int* __restrict__ starts, const int* __restrict__ perm,
    float* __restrict__ cs)
{
  __shared__ float Rl[64][NMX];
  __shared__ float Yl[64][NSPH];
  __shared__ int   spl[64];
  int atom = blockIdx.x;
  int tid = threadIdx.x;
  int e0 = starts[atom], e1 = starts[atom + 1];
  float px = pos[atom*3+0], py = pos[atom*3+1], pz = pos[atom*3+2];
  int sp = tid / 90, n = (tid % 90) / 9, k = tid % 9;
  float acc = 0.f;
  for (int base = e0; base < e1; base += 64){
    int nch = min(64, e1 - base);
    if (tid < nch){
      int e = perm[base + tid];
      int snd = ei[e];
      const float* C = cells + (size_t)batch[snd] * 9;
      float o0 = eoff[e*3+0], o1 = eoff[e*3+1], o2 = eoff[e*3+2];
      float rx = px - pos[snd*3+0] + o0*C[0] + o1*C[3] + o2*C[6];
      float ry = py - pos[snd*3+1] + o0*C[1] + o1*C[4] + o2*C[7];
      float rz = pz - pos[snd*3+2] + o0*C[2] + o1*C[5] + o2*C[8];
      float r = sqrtf(rx*rx + ry*ry + rz*rz + 1e-12f);
      float inv = 1.f / r;
      float hx = rx*inv, hy = ry*inv, hz = rz*inv;
      float fc = (r < 5.f) ? (0.5f * (__cosf(r * 0.6283185307179586f) + 1.f)) : 0.f;
      #pragma unroll
      for (int nn = 0; nn < NMX; nn++){
        float d = r - (5.f/9.f) * (float)nn;
        Rl[tid][nn] = __expf(-2.f * d * d) * fc;
      }
      Yl[tid][0] = 0.28209479177387814f;
      Yl[tid][1] = 0.4886025119029199f * hy;
      Yl[tid][2] = 0.4886025119029199f * hz;
      Yl[tid][3] = 0.4886025119029199f * hx;
      Yl[tid][4] = 1.0925484305920792f * hx * hy;
      Yl[tid][5] = 1.0925484305920792f * hy * hz;
      Yl[tid][6] = 0.31539156525252005f * (3.f * hz * hz - 1.f);
      Yl[tid][7] = 1.0925484305920792f * hx * hz;
      Yl[tid][8] = 0.5462742152960396f * (hx * hx - hy * hy);
      spl[tid] = numbers[snd];
    }
    __syncthreads();
    if (tid < 360){
      for (int j = 0; j < nch; j++){
        float v = Rl[j][n] * Yl[j][k];
        acc += (spl[j] == sp) ? v : 0.f;
      }
    }
    __syncthreads();
  }
  if (tid < 360) cs[(size_t)atom * 360 + tid] = acc;
}

// ---------------- species grouping ----------------
__global__ void k_count(const int* __restrict__ numbers, int* __restrict__ cnt){
  int i = blockIdx.x * 256 + threadIdx.x;
  if (i < NA) atomicAdd(&cnt[numbers[i]], 1);
}
__global__ void k_offs(const int* __restrict__ cnt, int* __restrict__ offs){
  if (threadIdx.x == 0){
    int o = 0;
    for (int s = 0; s < 4; s++){ offs[s] = o; o += cnt[s]; }
    offs[4] = o;
  }
}
__global__ void k_scatter(const int* __restrict__ numbers, const int* __restrict__ offs,
                          int* __restrict__ cursor, int* __restrict__ list){
  int i = blockIdx.x * 256 + threadIdx.x;
  if (i < NA){
    int s = numbers[i];
    int p = atomicAdd(&cursor[s], 1);
    list[offs[s] + p] = i;
  }
}

// ---------------- per-atom: mix cs->c, compute ps (bf16) + LN stats ----------------
__global__ __launch_bounds__(256) void k_ps(
    const float* __restrict__ cs, const float* __restrict__ U,
    unsigned short* __restrict__ ps, float* __restrict__ stats)
{
  __shared__ float csr[360];
  __shared__ float cl[360];
  __shared__ float red[16];
  __shared__ float ul[16];
  int i = blockIdx.x, tid = threadIdx.x;
  if (tid < 16) ul[tid] = U[tid];
  for (int j = tid; j < 360; j += 256) csr[j] = cs[(size_t)i * 360 + j];
  __syncthreads();
  for (int j = tid; j < 360; j += 256){
    int a = j / 90, nk = j % 90;
    cl[j] = ul[a*4+0]*csr[nk] + ul[a*4+1]*csr[90+nk]
          + ul[a*4+2]*csr[180+nk] + ul[a*4+3]*csr[270+nk];
  }
  __syncthreads();
  float s1 = 0.f, s2 = 0.f;
  const float rs3 = 0.5773502691896258f, rs5 = 0.4472135954999579f;
  for (int f = tid; f < FF; f += 256){
    int l = f % 3, qp = f / 3;
    int q = qp / 40, p = qp - q * 40;
    const float* cq = &cl[q * 9];
    const float* cp = &cl[p * 9];
    float v;
    if (l == 0)      v = cq[0]*cp[0];
    else if (l == 1) v = (cq[1]*cp[1] + cq[2]*cp[2] + cq[3]*cp[3]) * rs3;
    else             v = (cq[4]*cp[4] + cq[5]*cp[5] + cq[6]*cp[6] + cq[7]*cp[7] + cq[8]*cp[8]) * rs5;
    ps[(size_t)i * FF + f] = f2bf(v);
    s1 += v; s2 += v * v;
  }
  #pragma unroll
  for (int m = 32; m; m >>= 1){ s1 += __shfl_xor(s1, m, 64); s2 += __shfl_xor(s2, m, 64); }
  int w = tid >> 6, lane = tid & 63;
  if (lane == 0){ red[w] = s1; red[8 + w] = s2; }
  __syncthreads();
  if (tid == 0){
    float t1 = red[0] + red[1] + red[2] + red[3];
    float t2 = red[8] + red[9] + red[10] + red[11];
    float mean = t1 * (1.f / FF);
    float var = t2 * (1.f / FF) - mean * mean;
    var = fmaxf(var, 0.f);
    stats[2*i]   = mean;
    stats[2*i+1] = rsqrtf(var + 1e-5f);
  }
}

// ---------------- weight prep ----------------
__global__ __launch_bounds__(256) void k_wg1(
    const float* __restrict__ W1, const float* __restrict__ U,
    const float* __restrict__ gamma, const float* __restrict__ beta,
    unsigned short* __restrict__ Wg, float* __restrict__ gW, float* __restrict__ bW)
{
  __shared__ float tg[64][65];
  __shared__ float tb[64][65];
  int n0 = blockIdx.x * 64, f0 = blockIdx.y * 64, s = blockIdx.z;
  float u0 = U[s], u1 = U[4+s], u2 = U[8+s], u3 = U[12+s];
  int tid = threadIdx.x;
  #pragma unroll 4
  for (int rep = 0; rep < 16; rep++){
    int idx = rep * 256 + tid;
    int fi = idx >> 6, ni = idx & 63;
    size_t base = (size_t)(f0 + fi) * 512 + (n0 + ni);
    float w = u0*W1[base] + u1*W1[base + (size_t)FF*512]
            + u2*W1[base + (size_t)2*FF*512] + u3*W1[base + (size_t)3*FF*512];
    tg[fi][ni] = gamma[f0 + fi] * w;
    tb[fi][ni] = beta[f0 + fi] * w;
  }
  __syncthreads();
  #pragma unroll 4
  for (int rep = 0; rep < 16; rep++){
    int idx = rep * 256 + tid;
    int ni = idx >> 6, fi = idx & 63;
    Wg[((size_t)s * 512 + n0 + ni) * FF + f0 + fi] = f2bf(tg[fi][ni]);
  }
  if (tid < 64){
    float sg = 0.f, sb = 0.f;
    for (int fi = 0; fi < 64; fi++){ sg += tg[fi][tid]; sb += tb[fi][tid]; }
    atomic_add_f(&gW[s * 512 + n0 + tid], sg);
    atomic_add_f(&bW[s * 512 + n0 + tid], sb);
  }
}

__global__ __launch_bounds__(256) void k_w2t(
    const float* __restrict__ W2, const float* __restrict__ U,
    unsigned short* __restrict__ W2t)
{
  __shared__ float t[64][65];
  int n0 = blockIdx.x * 64, k0 = blockIdx.y * 64, s = blockIdx.z;
  float u0 = U[s], u1 = U[4+s], u2 = U[8+s], u3 = U[12+s];
  int tid = threadIdx.x;
  #pragma unroll 4
  for (int rep = 0; rep < 16; rep++){
    int idx = rep * 256 + tid;
    int ki = idx >> 6, ni = idx & 63;
    size_t base = (size_t)(k0 + ki) * 512 + (n0 + ni);
    t[ki][ni] = u0*W2[base] + u1*W2[base + 512*512]
              + u2*W2[base + 2*512*512] + u3*W2[base + 3*512*512];
  }
  __syncthreads();
  #pragma unroll 4
  for (int rep = 0; rep < 16; rep++){
    int idx = rep * 256 + tid;
    int ni = idx >> 6, ki = idx & 63;
    W2t[((size_t)s * 512 + n0 + ni) * 512 + k0 + ki] = f2bf(t[ki][ni]);
  }
}

__global__ void k_w3(const float* __restrict__ W3, const float* __restrict__ U,
                     float* __restrict__ W3s)
{
  int idx = blockIdx.x * 256 + threadIdx.x;
  if (idx < 4 * 512){
    int s = idx >> 9, k = idx & 511;
    W3s[idx] = U[s]*W3[k] + U[4+s]*W3[512+k] + U[8+s]*W3[2*512+k] + U[12+s]*W3[3*512+k];
  }
}

// ---------------- GEMM: gathered rows (species-grouped) x Bt[s][N][K], bf16 MFMA ------
// grid.x = n-block (4 adjacent blocks share the A tile -> L2 locality), grid.y = row tile
template<int EPI>
__global__ __launch_bounds__(256) void k_gemm(
    const unsigned short* __restrict__ Ag, int lda, int K,
    const unsigned short* __restrict__ Btg,
    const int* __restrict__ list, const int* __restrict__ offs, const int* __restrict__ cnt,
    const float* __restrict__ stats, const float* __restrict__ gW, const float* __restrict__ bW,
    unsigned short* __restrict__ out)
{
  __shared__ alignas(16) char smem[32768]; // A: [128][64]bf16 (16KB) + B: [128][64]bf16
  int t = blockIdx.y, s = 0;
  for (; s < 4; s++){
    int nts = (cnt[s] + 127) >> 7;
    if (t < nts) break;
    t -= nts;
  }
  if (s >= 4) return;
  int cntS = cnt[s], offS = offs[s];
  int rt = t, n0 = blockIdx.x * 128;
  int tid = threadIdx.x, w = tid >> 6, lane = tid & 63;
  int wr = w >> 1, wc = w & 1;

  const unsigned short* Bts = Btg + (size_t)s * 512 * K;
  const unsigned short* gA[4];
  const unsigned short* gB[4];
  char* lA[4];
  char* lB[4];
  #pragma unroll
  for (int it = 0; it < 4; it++){
    int g = it * 4 + w;
    int idx = g * 64 + lane;
    int row = idx >> 3, ch = idx & 7;
    int cg = ch ^ (row & 7);
    int gr = rt * 128 + row; gr = gr < cntS ? gr : cntS - 1;
    int atom = list[offS + gr];
    gA[it] = Ag + (size_t)atom * lda + cg * 8;
    lA[it] = smem + g * 1024;
    gB[it] = Bts + (size_t)(n0 + row) * K + cg * 8;
    lB[it] = smem + 16384 + g * 1024;
  }

  int hi = lane >> 4, lo = lane & 15;
  f32x4 acc[4][4];
  #pragma unroll
  for (int mi = 0; mi < 4; mi++)
    #pragma unroll
    for (int ni = 0; ni < 4; ni++)
      #pragma unroll
      for (int r = 0; r < 4; r++) acc[mi][ni][r] = 0.f;

  int abase[4], a7[4], bbase[4], b7[4];
  #pragma unroll
  for (int mi = 0; mi < 4; mi++){ int row = wr*64 + mi*16 + lo; abase[mi] = row*128; a7[mi] = row & 7; }
  #pragma unroll
  for (int ni = 0; ni < 4; ni++){ int row = wc*64 + ni*16 + lo; bbase[ni] = 16384 + row*128; b7[ni] = row & 7; }

  for (int kt = 0; kt < K; kt += 64){
    #pragma unroll
    for (int it = 0; it < 4; it++) gload16(gA[it] + kt, lA[it]);
    #pragma unroll
    for (int it = 0; it < 4; it++) gload16(gB[it] + kt, lB[it]);
    __syncthreads();
    #pragma unroll
    for (int kk = 0; kk < 2; kk++){
      bf16x8 af[4], bfr[4];
      #pragma unroll
      for (int mi = 0; mi < 4; mi++)
        af[mi] = *(const bf16x8*)(smem + abase[mi] + (((kk*4 + hi) ^ a7[mi]) << 4));
      #pragma unroll
      for (int ni = 0; ni < 4; ni++)
        bfr[ni] = *(const bf16x8*)(smem + bbase[ni] + (((kk*4 + hi) ^ b7[ni]) << 4));
      #pragma unroll
      for (int mi = 0; mi < 4; mi++)
        #pragma unroll
        for (int ni = 0; ni < 4; ni++)
          acc[mi][ni] = __builtin_amdgcn_mfma_f32_16x16x32_bf16(af[mi], bfr[ni], acc[mi][ni], 0, 0, 0);
    }
    __syncthreads();
  }

  int gn[4]; float gwv[4], bwv[4];
  #pragma unroll
  for (int ni = 0; ni < 4; ni++){
    gn[ni] = n0 + wc*64 + ni*16 + lo;
    if (EPI == 1){ gwv[ni] = gW[s*512 + gn[ni]]; bwv[ni] = bW[s*512 + gn[ni]]; }
    else { gwv[ni] = 0.f; bwv[ni] = 0.f; }
  }
  #pragma unroll
  for (int mi = 0; mi < 4; mi++){
    #pragma unroll
    for (int j = 0; j < 4; j++){
      int gr = rt*128 + wr*64 + mi*16 + hi*4 + j;
      if (gr < cntS){
        int atom = list[offS + gr];
        float mean = 0.f, rstd = 0.f;
        if (EPI == 1){ mean = stats[2*atom]; rstd = stats[2*atom+1]; }
        #pragma unroll
        for (int ni = 0; ni < 4; ni++){
          float v = acc[mi][ni][j];
          if (EPI == 1) v = rstd * v + bwv[ni] - mean * rstd * gwv[ni];
          v = silu(v);
          out[(size_t)atom * 512 + gn[ni]] = f2bf(v);
        }
      }
    }
  }
}

// ---------------- final: per-atom dot(h2, W3s[s]) -> molecule segment sum -------------
__global__ __launch_bounds__(256) void k_final(
    const unsigned short* __restrict__ h2, const float* __restrict__ W3s,
    const int* __restrict__ numbers, const int* __restrict__ batch,
    const float* __restrict__ Wc, float* __restrict__ out)
{
  int wid = threadIdx.x >> 6, lane = threadIdx.x & 63;
  int atom = blockIdx.x * 4 + wid;
  if (atom >= NA) return;
  int sp = numbers[atom];
  const unsigned short* hp = h2 + (size_t)atom * 512 + lane * 8;
  const float* wp = W3s + sp * 512 + lane * 8;
  float acc = 0.f;
  #pragma unroll
  for (int j = 0; j < 8; j++) acc += bf2f(hp[j]) * wp[j];
  #pragma unroll
  for (int m = 32; m; m >>= 1) acc += __shfl_xor(acc, m, 64);
  if (lane == 0){
    float val = acc * (1.f / 128.f) + Wc[sp];
    atomic_add_f(&out[batch[atom]], val);
  }
}

extern "C" void kernel_launch(void* const* d_in, const int* in_sizes, int n_in,
                              void* d_out, int out_size, void* d_ws, size_t ws_size,
                              hipStream_t stream)
{
  const float* pos     = (const float*)d_in[0];
  const float* cells   = (const float*)d_in[1];
  const int*   numbers = (const int*)d_in[2];
  const int*   ei      = (const int*)d_in[3];
  const float* eoff    = (const float*)d_in[4];
  const int*   batch   = (const int*)d_in[5];
  const float* U       = (const float*)d_in[6];
  const float* gamma   = (const float*)d_in[7];
  const float* beta    = (const float*)d_in[8];
  const float* W1      = (const float*)d_in[9];
  const float* W2      = (const float*)d_in[10];
  const float* W3      = (const float*)d_in[11];
  const float* Wc      = (const float*)d_in[12];
  float* out = (float*)d_out;

  char* ws = (char*)d_ws;
  size_t off = 0;
  auto alloc = [&](size_t bytes) -> void* {
    void* p = ws + off;
    off += (bytes + 255) & ~(size_t)255;
    return p;
  };
  unsigned short* ps  = (unsigned short*)alloc((size_t)NA * FF * 2);   // 157 MB
  float* cs           = (float*)alloc((size_t)NA * 360 * 4);           // 23.6 MB
  float* stats        = (float*)alloc((size_t)NA * 2 * 4);
  unsigned short* Wg1 = (unsigned short*)alloc((size_t)4 * 512 * FF * 2); // 19.7 MB
  float* gW           = (float*)alloc(4 * 512 * 4);
  float* bW           = (float*)alloc(4 * 512 * 4);
  unsigned short* W2t = (unsigned short*)alloc((size_t)4 * 512 * 512 * 2);
  float* W3s          = (float*)alloc(4 * 512 * 4);
  unsigned short* h1  = (unsigned short*)alloc((size_t)NA * 512 * 2);
  unsigned short* h2  = (unsigned short*)alloc((size_t)NA * 512 * 2);
  int* list           = (int*)alloc(NA * 4);
  int* perm           = (int*)alloc((size_t)NE * 4);                   // 2 MB
  int* starts         = (int*)alloc((NA + 1) * 4);
  int* cnt16k         = (int*)alloc(NA * 4);
  int* cursor16k      = (int*)alloc(NA * 4);
  int* ints           = (int*)alloc(64);
  int* cnt = ints; int* cursor = ints + 4; int* offs = ints + 8;

  hipMemsetAsync(ints, 0, 64, stream);
  hipMemsetAsync(cnt16k, 0, NA * 4, stream);
  hipMemsetAsync(gW, 0, 4 * 512 * 4, stream);
  hipMemsetAsync(bW, 0, 4 * 512 * 4, stream);
  hipMemsetAsync(out, 0, (size_t)out_size * 4, stream);

  // edge grouping by receiver, then atomic-free accumulation
  k_hist<<<NE / 256, 256, 0, stream>>>(ei, cnt16k);
  k_scan<<<1, 256, 0, stream>>>(cnt16k, starts, cursor16k);
  k_sortperm<<<NE / 256, 256, 0, stream>>>(ei, cursor16k, perm);
  k_edges2<<<NA, 384, 0, stream>>>(pos, cells, numbers, ei, eoff, batch, starts, perm, cs);

  // species grouping
  k_count<<<NA / 256, 256, 0, stream>>>(numbers, cnt);
  k_offs<<<1, 64, 0, stream>>>(cnt, offs);
  k_scatter<<<NA / 256, 256, 0, stream>>>(numbers, offs, cursor, list);

  k_ps<<<NA, 256, 0, stream>>>(cs, U, ps, stats);
  k_wg1<<<dim3(8, 75, 4), 256, 0, stream>>>(W1, U, gamma, beta, Wg1, gW, bW);
  k_w2t<<<dim3(8, 8, 4), 256, 0, stream>>>(W2, U, W2t);
  k_w3<<<8, 256, 0, stream>>>(W3, U, W3s);
  k_gemm<1><<<dim3(4, 132), 256, 0, stream>>>(ps, FF, FF, Wg1, list, offs, cnt, stats, gW, bW, h1);
  k_gemm<2><<<dim3(4, 132), 256, 0, stream>>>(h1, 512, 512, W2t, list, offs, cnt, stats, gW, bW, h2);
  k_final<<<NA / 4, 256, 0, stream>>>(h2, W3s, numbers, batch, Wc, out);
}